// Round 5
// baseline (158.501 us; speedup 1.0000x reference)
//
#include <hip/hip_runtime.h>
#include <hip/hip_bf16.h>

// Problem constants (match reference)
constexpr int B   = 64;
constexpr int D   = 8192;
constexpr int DE  = 256;
constexpr int DQK = 256;
constexpr float SCALE = 0.0625f;  // 1/sqrt(256)

constexpr int KC = 64;            // k-chunks in K1 (128 d each)
constexpr int KD = D / KC;        // 128

// Workspace layout (float offsets)
constexpr size_t OFF_XT    = 0;          // XT[D][B]            = 524288
constexpr size_t OFF_WPART = 524288;     // [KC][256 t][64 b]   = 1048576
constexpr size_t OFF_SPART = 1572864;    // [KC][64 b]          = 4096
constexpr size_t OFF_WBT   = 1576960;    // W[b][t]             = 16384
constexpr size_t OFF_S     = 1593344;    // s[64]
constexpr size_t OFF_ZTB   = 1593408;    // Z[t][b]             = 16384
constexpr size_t OFF_C     = 1609792;    // c[64]

// ---------------------------------------------------------------------------
// K0: transpose X[64][8192] -> XT[8192][64].  Grid 128 blocks (64 d x 64 b).
// ---------------------------------------------------------------------------
__global__ __launch_bounds__(256) void k0_transpose(
    const float* __restrict__ x, float* __restrict__ ws)
{
    float* XT = ws + OFF_XT;
    const int d0 = blockIdx.x * 64;
    const int tid = threadIdx.x;
    __shared__ float T[64][65];

    #pragma unroll
    for (int i = 0; i < 16; ++i) {
        int idx = i * 256 + tid;
        int r = idx >> 6, c = idx & 63;          // r=b, c=d-local
        T[r][c] = x[(size_t)r * D + d0 + c];
    }
    __syncthreads();
    #pragma unroll
    for (int i = 0; i < 16; ++i) {
        int idx = i * 256 + tid;
        int dd = idx >> 6, bb = idx & 63;
        XT[(size_t)(d0 + dd) * B + bb] = T[bb][dd];
    }
}

// ---------------------------------------------------------------------------
// K1: partial W.  Grid (KC, 8 tgroups) x 256 threads; wave handles 8 t's.
//   WPART[kc][t][b] = sum_{d in chunk} XT[d][b] * E[d+1][t]
//   SPART[kc][b]    = sum_{d in chunk} XT[d][b]      (tg 0, wave 0)
// ---------------------------------------------------------------------------
__global__ __launch_bounds__(256) void k1_wpart(
    const float* __restrict__ E, float* __restrict__ ws)
{
    const float* XT = ws + OFF_XT;
    const int kc = blockIdx.x;
    const int tg = blockIdx.y;
    const int tid = threadIdx.x;
    const int lane = tid & 63;
    const int wv   = tid >> 6;
    const int t0   = tg * 32 + wv * 8;
    const int dbase = kc * KD;

    float acc[8] = {0,0,0,0,0,0,0,0};
    float acc_s = 0.f;

    #pragma unroll 4
    for (int d = 0; d < KD; ++d) {
        const int dd = dbase + d;
        const float xt = XT[(size_t)dd * B + lane];
        const float4 e4a = *reinterpret_cast<const float4*>(E + (size_t)(dd + 1) * DE + t0);
        const float4 e4b = *reinterpret_cast<const float4*>(E + (size_t)(dd + 1) * DE + t0 + 4);
        acc[0] += xt * e4a.x; acc[1] += xt * e4a.y;
        acc[2] += xt * e4a.z; acc[3] += xt * e4a.w;
        acc[4] += xt * e4b.x; acc[5] += xt * e4b.y;
        acc[6] += xt * e4b.z; acc[7] += xt * e4b.w;
        acc_s += xt;
    }
    float* WP = ws + OFF_WPART;
    #pragma unroll
    for (int j = 0; j < 8; ++j)
        WP[((size_t)kc * 256 + t0 + j) * B + lane] = acc[j];
    if (tg == 0 && wv == 0)
        ws[OFF_SPART + (size_t)kc * B + lane] = acc_s;
}

// ---------------------------------------------------------------------------
// K1b: reduce partials.  Grid 64 x 256.  W_bt[b][t] = sum_kc WPART[kc][t][b].
//      Block 0 also reduces s.
// ---------------------------------------------------------------------------
__global__ __launch_bounds__(256) void k1b_reduce(float* __restrict__ ws)
{
    const int g = blockIdx.x * 256 + threadIdx.x;   // 0..16383
    const int t = g >> 6, b = g & 63;
    const float* WP = ws + OFF_WPART;
    float acc = 0.f;
    #pragma unroll 8
    for (int kc = 0; kc < KC; ++kc)
        acc += WP[(size_t)kc * 16384 + t * 64 + b];
    ws[OFF_WBT + (size_t)b * 256 + t] = acc;

    if (blockIdx.x == 0 && threadIdx.x < 64) {
        float s = 0.f;
        #pragma unroll 8
        for (int kc = 0; kc < KC; ++kc)
            s += ws[OFF_SPART + (size_t)kc * B + threadIdx.x];
        ws[OFF_S + threadIdx.x] = s;
    }
}

// ---------------------------------------------------------------------------
// K2: per batch b (64 blocks x 256):
//   U[o] = SCALE*(dot(w, Wq[o,:]) + s*bq[o])
//   Z[t][b] = sum_o U[o]*Wk[o][t];   c[b] = sum_o U[o]*bk[o]
// ---------------------------------------------------------------------------
__global__ __launch_bounds__(256) void k2_uzc(
    const float* __restrict__ Wq, const float* __restrict__ bq,
    const float* __restrict__ Wk, const float* __restrict__ bk,
    float* __restrict__ ws)
{
    const int b   = blockIdx.x;
    const int tid = threadIdx.x;
    const int lane = tid & 63;
    const int wv   = tid >> 6;

    __shared__ float w_lds[256];
    __shared__ float U_lds[256];

    w_lds[tid] = ws[OFF_WBT + (size_t)b * 256 + tid];
    const float sVal = ws[OFF_S + b];
    __syncthreads();

    // U phase: wave wv handles o = wv*64 .. +63
    const float4 wl4 = *reinterpret_cast<const float4*>(&w_lds[4 * lane]);
    for (int i = 0; i < 64; ++i) {
        const int o = wv * 64 + i;
        const float4 q4 = *reinterpret_cast<const float4*>(Wq + (size_t)o * DE + 4 * lane);
        float dot = q4.x * wl4.x + q4.y * wl4.y + q4.z * wl4.z + q4.w * wl4.w;
        for (int off = 32; off; off >>= 1) dot += __shfl_xor(dot, off);
        if (lane == 0) U_lds[o] = SCALE * (dot + sVal * bq[o]);
    }
    __syncthreads();

    // Z phase: t = wv*64 + lane
    {
        const int t = wv * 64 + lane;
        float z0 = 0.f, z1 = 0.f, z2 = 0.f, z3 = 0.f;
        #pragma unroll 4
        for (int o = 0; o < DQK; o += 4) {
            z0 += U_lds[o + 0] * Wk[(size_t)(o + 0) * DE + t];
            z1 += U_lds[o + 1] * Wk[(size_t)(o + 1) * DE + t];
            z2 += U_lds[o + 2] * Wk[(size_t)(o + 2) * DE + t];
            z3 += U_lds[o + 3] * Wk[(size_t)(o + 3) * DE + t];
        }
        ws[OFF_ZTB + (size_t)t * B + b] = (z0 + z1) + (z2 + z3);
    }

    // c phase: wave 0
    if (wv == 0) {
        const float4 u4 = *reinterpret_cast<const float4*>(&U_lds[4 * lane]);
        const float4 k4 = *reinterpret_cast<const float4*>(bk + 4 * lane);
        float dot = u4.x * k4.x + u4.y * k4.y + u4.z * k4.z + u4.w * k4.w;
        for (int off = 32; off; off >>= 1) dot += __shfl_xor(dot, off);
        if (lane == 0) ws[OFF_C + b] = dot;
    }
}

// ---------------------------------------------------------------------------
// K3: F[d][b] = sum_t E[d+1][t]*Z[t][b];  y = x*(1 + F + c).
// Grid 128 blocks; block owns 64 d-rows x all 64 b.
// Thread owns 4d x 4b; k-loop in 4 steps of 64 t with E-tile in LDS.
// ---------------------------------------------------------------------------
__global__ __launch_bounds__(256) void k3_fy(
    const float* __restrict__ x, const float* __restrict__ E,
    const float* __restrict__ ws, float* __restrict__ y)
{
    const int d0  = blockIdx.x * 64;
    const int tid = threadIdx.x;
    const int dq  = tid >> 4;      // 0..15 -> d = 4*dq
    const int bq4 = tid & 15;      // 0..15 -> b = 4*bq4

    __shared__ float Zl[256][64];     // 64 KB
    __shared__ float Et[64][65];      // 16.6 KB (reused as Fl)

    // stage Z (linear copy; Z_tb layout matches [t][b])
    {
        const float* Zsrc = ws + OFF_ZTB;
        float* Zdst = &Zl[0][0];
        #pragma unroll
        for (int i = 0; i < 64; ++i)
            Zdst[i * 256 + tid] = Zsrc[i * 256 + tid];
    }
    __syncthreads();

    float acc[4][4];
    #pragma unroll
    for (int i = 0; i < 4; ++i)
        #pragma unroll
        for (int j = 0; j < 4; ++j) acc[i][j] = 0.f;

    for (int ks = 0; ks < 4; ++ks) {
        const int t0 = ks * 64;
        // stage E tile [64 d][64 t], row-major, padded
        #pragma unroll
        for (int i = 0; i < 16; ++i) {
            int idx = i * 256 + tid;
            int r = idx >> 6, c = idx & 63;
            Et[r][c] = E[(size_t)(d0 + r + 1) * DE + t0 + c];
        }
        __syncthreads();
        #pragma unroll 4
        for (int tt = 0; tt < 64; ++tt) {
            const float4 z4 = *reinterpret_cast<const float4*>(&Zl[t0 + tt][4 * bq4]);
            const float e0 = Et[4 * dq + 0][tt];
            const float e1 = Et[4 * dq + 1][tt];
            const float e2 = Et[4 * dq + 2][tt];
            const float e3 = Et[4 * dq + 3][tt];
            acc[0][0] += e0 * z4.x; acc[0][1] += e0 * z4.y; acc[0][2] += e0 * z4.z; acc[0][3] += e0 * z4.w;
            acc[1][0] += e1 * z4.x; acc[1][1] += e1 * z4.y; acc[1][2] += e1 * z4.z; acc[1][3] += e1 * z4.w;
            acc[2][0] += e2 * z4.x; acc[2][1] += e2 * z4.y; acc[2][2] += e2 * z4.z; acc[2][3] += e2 * z4.w;
            acc[3][0] += e3 * z4.x; acc[3][1] += e3 * z4.y; acc[3][2] += e3 * z4.z; acc[3][3] += e3 * z4.w;
        }
        __syncthreads();
    }

    // stash F into LDS (reuse Et): Fl[d_local][b]
    #pragma unroll
    for (int i = 0; i < 4; ++i)
        #pragma unroll
        for (int j = 0; j < 4; ++j)
            Et[4 * dq + i][4 * bq4 + j] = acc[i][j];
    __syncthreads();

    // y = x * (1 + F + c): thread -> (b = tid>>2, 16 d's)
    {
        const int b  = tid >> 2;
        const int ds = (tid & 3) * 16;
        const float cc = ws[OFF_C + b];
        const float* xr = x + (size_t)b * D + d0 + ds;
        float*       yr = y + (size_t)b * D + d0 + ds;
        #pragma unroll
        for (int k4 = 0; k4 < 4; ++k4) {
            float4 xv = *reinterpret_cast<const float4*>(xr + 4 * k4);
            float4 yv;
            yv.x = xv.x * (1.f + Et[ds + 4 * k4 + 0][b] + cc);
            yv.y = xv.y * (1.f + Et[ds + 4 * k4 + 1][b] + cc);
            yv.z = xv.z * (1.f + Et[ds + 4 * k4 + 2][b] + cc);
            yv.w = xv.w * (1.f + Et[ds + 4 * k4 + 3][b] + cc);
            *reinterpret_cast<float4*>(yr + 4 * k4) = yv;
        }
    }
}

extern "C" void kernel_launch(void* const* d_in, const int* in_sizes, int n_in,
                              void* d_out, int out_size, void* d_ws, size_t ws_size,
                              hipStream_t stream) {
    // inputs: t, x[B*D], E[(D+1)*DE], Wq[DQK*DE], bq[DQK], Wk[DQK*DE], bk[DQK]
    const float* x  = (const float*)d_in[1];
    const float* E  = (const float*)d_in[2];
    const float* Wq = (const float*)d_in[3];
    const float* bq = (const float*)d_in[4];
    const float* Wk = (const float*)d_in[5];
    const float* bk = (const float*)d_in[6];
    float* y  = (float*)d_out;
    float* ws = (float*)d_ws;

    hipLaunchKernelGGL(k0_transpose, dim3(128),       dim3(256), 0, stream, x, ws);
    hipLaunchKernelGGL(k1_wpart,     dim3(KC, 8),     dim3(256), 0, stream, E, ws);
    hipLaunchKernelGGL(k1b_reduce,   dim3(64),        dim3(256), 0, stream, ws);
    hipLaunchKernelGGL(k2_uzc,       dim3(B),         dim3(256), 0, stream, Wq, bq, Wk, bk, ws);
    hipLaunchKernelGGL(k3_fy,        dim3(128),       dim3(256), 0, stream, x, E, ws, y);
}

// Round 7
// 115.622 us; speedup vs baseline: 1.3709x; 1.3709x over previous
//
#include <hip/hip_runtime.h>
#include <hip/hip_bf16.h>

// Problem constants (match reference)
constexpr int B   = 64;
constexpr int D   = 8192;
constexpr int DE  = 256;
constexpr int DQK = 256;
constexpr float SCALE = 0.0625f;  // 1/sqrt(256)

constexpr int NKC = 64;           // d-chunks
constexpr int KD  = D / NKC;      // 128 d per chunk

// Workspace layout (float offsets)
constexpr size_t OFF_MT    = 0;          // [256 d2][256 t]           = 65536
constexpr size_t OFF_AUX   = 65536;      // m0[256], g1[256], g0 (576 reserved)
constexpr size_t OFF_WPART = 66112;      // [64 kc][64 b][256 t]      = 1048576
constexpr size_t OFF_Z     = 1114688;    // Z[t][b]                   = 16384
constexpr size_t OFF_C     = 1131072;    // c[64]

// ---------------------------------------------------------------------------
// KA: blocks 0..255  : WPART[kc][b][t0..t0+63] = sum_{d in chunk} x[b][d]*E[d+1][t]
//     blocks 256..319: MT[i][j] = SCALE * sum_o Wq[o][i]*Wk[o][j]  (32x32 tiles)
//     block  320     : aux = {m0, g1, g0}
// ---------------------------------------------------------------------------
__global__ __launch_bounds__(256, 2) void kA(
    const float* __restrict__ x, const float* __restrict__ E,
    const float* __restrict__ Wq, const float* __restrict__ bq,
    const float* __restrict__ Wk, const float* __restrict__ bk,
    float* __restrict__ ws)
{
    __shared__ __align__(16) char smem[68608];
    const int blk = blockIdx.x;
    const int tid = threadIdx.x;

    if (blk < 256) {
        // ---- W-partial GEMM tile: 64 b x 64 t x 128 d ----
        const int kc  = blk >> 2;
        const int tqb = blk & 3;
        float (*Xl)[132] = (float(*)[132])smem;             // [64 b][128 d] padded
        float (*Et)[68]  = (float(*)[68])(smem + 33792);    // [128 d][64 t] padded

        // stage X chunk (coalesced float4)
        #pragma unroll
        for (int i = 0; i < 8; ++i) {
            int f4 = i * 256 + tid;            // [64 rows][32 f4]
            int r = f4 >> 5, c4 = f4 & 31;
            float4 v = *reinterpret_cast<const float4*>(
                x + (size_t)r * D + kc * KD + 4 * c4);
            *reinterpret_cast<float4*>(&Xl[r][4 * c4]) = v;
        }
        // stage E tile (coalesced float4)
        #pragma unroll
        for (int i = 0; i < 8; ++i) {
            int f4 = i * 256 + tid;            // [128 rows][16 f4]
            int r = f4 >> 4, c4 = f4 & 15;
            float4 v = *reinterpret_cast<const float4*>(
                E + (size_t)(kc * KD + r + 1) * DE + tqb * 64 + 4 * c4);
            *reinterpret_cast<float4*>(&Et[r][4 * c4]) = v;
        }
        __syncthreads();

        const int bq4 = tid >> 4;   // 0..15 -> b = 4*bq4
        const int tq4 = tid & 15;   // 0..15 -> t = 4*tq4
        float acc[4][4] = {};
        #pragma unroll 4
        for (int k = 0; k < KD; ++k) {
            const float e0 = Et[k][4 * tq4 + 0];
            const float e1 = Et[k][4 * tq4 + 1];
            const float e2 = Et[k][4 * tq4 + 2];
            const float e3 = Et[k][4 * tq4 + 3];
            #pragma unroll
            for (int i = 0; i < 4; ++i) {
                const float xv = Xl[4 * bq4 + i][k];
                acc[i][0] += xv * e0; acc[i][1] += xv * e1;
                acc[i][2] += xv * e2; acc[i][3] += xv * e3;
            }
        }
        float* WP = ws + OFF_WPART + (size_t)kc * (64 * 256);
        #pragma unroll
        for (int i = 0; i < 4; ++i)
            *reinterpret_cast<float4*>(
                WP + (size_t)(4 * bq4 + i) * 256 + tqb * 64 + 4 * tq4) =
                make_float4(acc[i][0], acc[i][1], acc[i][2], acc[i][3]);
    } else if (blk < 320) {
        // ---- MT 32x32 tile ----
        const int mb = blk - 256;
        float (*Aq)[33] = (float(*)[33])smem;
        float (*Bk)[33] = (float(*)[33])(smem + 4224);
        const int bi = mb >> 3, bj = mb & 7;
        const int I0 = bi * 32, J0 = bj * 32;
        const int lr = tid >> 5;   // 0..7
        const int lc = tid & 31;   // 0..31
        float acc[4] = {0.f, 0.f, 0.f, 0.f};
        for (int oc = 0; oc < DQK; oc += 32) {
            #pragma unroll
            for (int r = 0; r < 4; ++r) {
                int oo = lr + 8 * r;
                Aq[oo][lc] = Wq[(size_t)(oc + oo) * DE + I0 + lc];
                Bk[oo][lc] = Wk[(size_t)(oc + oo) * DE + J0 + lc];
            }
            __syncthreads();
            #pragma unroll
            for (int oo = 0; oo < 32; ++oo) {
                float bv = Bk[oo][lc];
                #pragma unroll
                for (int r = 0; r < 4; ++r)
                    acc[r] += Aq[oo][lr + 8 * r] * bv;
            }
            __syncthreads();
        }
        float* MT = ws + OFF_MT;
        #pragma unroll
        for (int r = 0; r < 4; ++r)
            MT[(size_t)(I0 + lr + 8 * r) * DE + (J0 + lc)] = acc[r] * SCALE;
    } else {
        // ---- aux ----
        float* sb0 = (float*)smem;          // bq
        float* sb1 = sb0 + 256;             // bk
        float* rp  = sb1 + 256;
        float* aux = ws + OFF_AUX;
        sb0[tid] = bq[tid];
        sb1[tid] = bk[tid];
        __syncthreads();
        float a0 = 0.f, a1 = 0.f;
        #pragma unroll 8
        for (int o = 0; o < DQK; ++o) {
            a0 += Wk[(size_t)o * DE + tid] * sb0[o];
            a1 += Wq[(size_t)o * DE + tid] * sb1[o];
        }
        aux[tid]       = a0 * SCALE;   // m0
        aux[256 + tid] = a1 * SCALE;   // g1
        rp[tid] = sb0[tid] * sb1[tid];
        __syncthreads();
        if (tid < 128) rp[tid] += rp[tid + 128];
        __syncthreads();
        if (tid < 64) {
            float v = rp[tid] + rp[tid + 64];
            for (int off = 32; off; off >>= 1) v += __shfl_xor(v, off);
            if (tid == 0) aux[512] = v * SCALE;   // g0
        }
    }
}

// ---------------------------------------------------------------------------
// KB: per batch b (64 blocks x 256 threads, thread = t):
//   s = sum_d x[b][d];  w[t] = sum_kc WPART[kc][b][t];
//   Z[t][b] = sum_d2 w[d2]*MT[d2][t] + s*m0[t];   c[b] = g1.w + s*g0
// ---------------------------------------------------------------------------
__global__ __launch_bounds__(256) void kB(
    const float* __restrict__ x, float* __restrict__ ws)
{
    const int b   = blockIdx.x;
    const int tid = threadIdx.x;
    __shared__ float wl[256];
    __shared__ float red[256];
    __shared__ float s_s;

    // s[b]: tree reduce of x row (coalesced float4, no long shuffle chain)
    float ps = 0.f;
    const float4* xr = reinterpret_cast<const float4*>(x + (size_t)b * D);
    #pragma unroll 8
    for (int i = tid; i < D / 4; i += 256) {
        float4 v = xr[i];
        ps += (v.x + v.y) + (v.z + v.w);
    }
    red[tid] = ps;

    // w[t]: reduce partials
    float w = 0.f;
    #pragma unroll 8
    for (int kc = 0; kc < NKC; ++kc)
        w += ws[OFF_WPART + (size_t)kc * (64 * 256) + (size_t)b * 256 + tid];
    wl[tid] = w;
    __syncthreads();

    if (tid < 128) red[tid] += red[tid + 128];
    __syncthreads();
    if (tid < 64) {
        float v = red[tid] + red[tid + 64];
        for (int off = 32; off; off >>= 1) v += __shfl_xor(v, off);
        if (tid == 0) s_s = v;
    }
    __syncthreads();
    const float sv = s_s;

    // z[t] (t = tid): coalesced MT reads, independent loads, unroll 8
    float z = sv * ws[OFF_AUX + tid];
    #pragma unroll 8
    for (int d2 = 0; d2 < 256; ++d2)
        z += wl[d2] * ws[OFF_MT + (size_t)d2 * 256 + tid];
    ws[OFF_Z + (size_t)tid * B + b] = z;     // [t][b]

    // c[b]
    red[tid] = ws[OFF_AUX + 256 + tid] * w;
    __syncthreads();
    if (tid < 128) red[tid] += red[tid + 128];
    __syncthreads();
    if (tid < 64) {
        float v = red[tid] + red[tid + 64];
        for (int off = 32; off; off >>= 1) v += __shfl_xor(v, off);
        if (tid == 0) ws[OFF_C + b] = v + sv * ws[OFF_AUX + 512];
    }
}

// ---------------------------------------------------------------------------
// KC: 256 blocks x (32 d-rows x 64 b).  F[d][b] = sum_t E[d+1][t]*Z[t][b];
//     y = x*(1 + F + c).  Thread tile 2d x 4b.
// ---------------------------------------------------------------------------
__global__ __launch_bounds__(256, 2) void kC(
    const float* __restrict__ x, const float* __restrict__ E,
    const float* __restrict__ ws, float* __restrict__ y)
{
    const int d0  = blockIdx.x * 32;
    const int tid = threadIdx.x;

    __shared__ float Zl[256][64];     // 64 KB, [t][b]
    __shared__ float Et[32][68];      // E tile; reused as F after compute

    // stage Z: ALL 16384 floats (256 t x 64 b), linear coalesced copy
    #pragma unroll
    for (int i = 0; i < 64; ++i)
        (&Zl[0][0])[i * 256 + tid] = ws[OFF_Z + (size_t)i * 256 + tid];
    __syncthreads();

    const int dq  = tid >> 4;   // 0..15 -> d = 2*dq
    const int bq4 = tid & 15;   // 0..15 -> b = 4*bq4
    float acc[2][4] = {};

    for (int ks = 0; ks < 4; ++ks) {
        // stage E tile [32 d][64 t]
        #pragma unroll
        for (int i = 0; i < 2; ++i) {
            int f4 = i * 256 + tid;        // [32 rows][16 f4]
            int r = f4 >> 4, c4 = f4 & 15;
            float4 v = *reinterpret_cast<const float4*>(
                E + (size_t)(d0 + r + 1) * DE + ks * 64 + 4 * c4);
            *reinterpret_cast<float4*>(&Et[r][4 * c4]) = v;
        }
        __syncthreads();
        #pragma unroll 4
        for (int tt = 0; tt < 64; ++tt) {
            const float4 z4 = *reinterpret_cast<const float4*>(
                &Zl[ks * 64 + tt][4 * bq4]);
            const float e0 = Et[2 * dq + 0][tt];
            const float e1 = Et[2 * dq + 1][tt];
            acc[0][0] += e0 * z4.x; acc[0][1] += e0 * z4.y;
            acc[0][2] += e0 * z4.z; acc[0][3] += e0 * z4.w;
            acc[1][0] += e1 * z4.x; acc[1][1] += e1 * z4.y;
            acc[1][2] += e1 * z4.z; acc[1][3] += e1 * z4.w;
        }
        __syncthreads();
    }

    // stash F into Et storage: F[d_local][b]
    #pragma unroll
    for (int i = 0; i < 2; ++i)
        *reinterpret_cast<float4*>(&Et[2 * dq + i][4 * bq4]) =
            make_float4(acc[i][0], acc[i][1], acc[i][2], acc[i][3]);
    __syncthreads();

    // y = x * (1 + F + c): thread -> b = tid>>2, 8 d's
    {
        const int b  = tid >> 2;
        const int ds = (tid & 3) * 8;
        const float cc = ws[OFF_C + b];
        const float* xr = x + (size_t)b * D + d0 + ds;
        float*       yr = y + (size_t)b * D + d0 + ds;
        #pragma unroll
        for (int k4 = 0; k4 < 2; ++k4) {
            float4 xv = *reinterpret_cast<const float4*>(xr + 4 * k4);
            float4 yv;
            yv.x = xv.x * (1.f + Et[ds + 4 * k4 + 0][b] + cc);
            yv.y = xv.y * (1.f + Et[ds + 4 * k4 + 1][b] + cc);
            yv.z = xv.z * (1.f + Et[ds + 4 * k4 + 2][b] + cc);
            yv.w = xv.w * (1.f + Et[ds + 4 * k4 + 3][b] + cc);
            *reinterpret_cast<float4*>(yr + 4 * k4) = yv;
        }
    }
}

extern "C" void kernel_launch(void* const* d_in, const int* in_sizes, int n_in,
                              void* d_out, int out_size, void* d_ws, size_t ws_size,
                              hipStream_t stream) {
    // inputs: t, x[B*D], E[(D+1)*DE], Wq[DQK*DE], bq[DQK], Wk[DQK*DE], bk[DQK]
    const float* x  = (const float*)d_in[1];
    const float* E  = (const float*)d_in[2];
    const float* Wq = (const float*)d_in[3];
    const float* bq = (const float*)d_in[4];
    const float* Wk = (const float*)d_in[5];
    const float* bk = (const float*)d_in[6];
    float* y  = (float*)d_out;
    float* ws = (float*)d_ws;

    hipLaunchKernelGGL(kA, dim3(321), dim3(256), 0, stream, x, E, Wq, bq, Wk, bk, ws);
    hipLaunchKernelGGL(kB, dim3(B),   dim3(256), 0, stream, x, ws);
    hipLaunchKernelGGL(kC, dim3(256), dim3(256), 0, stream, x, E, ws, y);
}

// Round 8
// 109.842 us; speedup vs baseline: 1.4430x; 1.0526x over previous
//
#include <hip/hip_runtime.h>
#include <hip/hip_bf16.h>

// Problem constants (match reference)
constexpr int B   = 64;
constexpr int D   = 8192;
constexpr int DE  = 256;
constexpr int DQK = 256;
constexpr float SCALE = 0.0625f;  // 1/sqrt(256)

constexpr int NKC = 64;           // d-chunks
constexpr int KD  = D / NKC;      // 128 d per chunk

// Workspace layout (float offsets)
constexpr size_t OFF_MT    = 0;          // [256 d2][256 t]           = 65536
constexpr size_t OFF_AUX   = 65536;      // m0[256], g1[256], g0 (576 reserved)
constexpr size_t OFF_WPART = 66112;      // [64 kc][64 b][256 t]      = 1048576
constexpr size_t OFF_Z     = 1114688;    // Z[t][b]                   = 16384
constexpr size_t OFF_C     = 1131072;    // c[64]

// ---------------------------------------------------------------------------
// KA: blocks 0..255  : WPART[kc][b][t0..t0+63] = sum_{d in chunk} x[b][d]*E[d+1][t]
//     blocks 256..319: MT[i][j] = SCALE * sum_o Wq[o][i]*Wk[o][j]  (32x32 tiles)
//     block  320     : aux = {m0, g1, g0}
// ---------------------------------------------------------------------------
__global__ __launch_bounds__(256, 2) void kA(
    const float* __restrict__ x, const float* __restrict__ E,
    const float* __restrict__ Wq, const float* __restrict__ bq,
    const float* __restrict__ Wk, const float* __restrict__ bk,
    float* __restrict__ ws)
{
    __shared__ __align__(16) char smem[68608];
    const int blk = blockIdx.x;
    const int tid = threadIdx.x;

    if (blk < 256) {
        // ---- W-partial GEMM tile: 64 b x 64 t x 128 d ----
        const int kc  = blk >> 2;
        const int tqb = blk & 3;
        float (*Xl)[132] = (float(*)[132])smem;             // [64 b][128 d] padded (132*4=528, 16B-aligned rows)
        float (*Et)[68]  = (float(*)[68])(smem + 33792);    // [128 d][64 t] padded (68*4=272, 16B-aligned rows)

        // stage X chunk (coalesced float4)
        #pragma unroll
        for (int i = 0; i < 8; ++i) {
            int f4 = i * 256 + tid;            // [64 rows][32 f4]
            int r = f4 >> 5, c4 = f4 & 31;
            float4 v = *reinterpret_cast<const float4*>(
                x + (size_t)r * D + kc * KD + 4 * c4);
            *reinterpret_cast<float4*>(&Xl[r][4 * c4]) = v;
        }
        // stage E tile (coalesced float4)
        #pragma unroll
        for (int i = 0; i < 8; ++i) {
            int f4 = i * 256 + tid;            // [128 rows][16 f4]
            int r = f4 >> 4, c4 = f4 & 15;
            float4 v = *reinterpret_cast<const float4*>(
                E + (size_t)(kc * KD + r + 1) * DE + tqb * 64 + 4 * c4);
            *reinterpret_cast<float4*>(&Et[r][4 * c4]) = v;
        }
        __syncthreads();

        const int bq4 = tid >> 4;   // 0..15 -> b = 4*bq4
        const int tq4 = tid & 15;   // 0..15 -> t = 4*tq4
        float acc[4][4] = {};
        #pragma unroll 2
        for (int k0 = 0; k0 < KD; k0 += 4) {
            float4 xv[4], ev[4];
            #pragma unroll
            for (int i = 0; i < 4; ++i)
                xv[i] = *reinterpret_cast<const float4*>(&Xl[4 * bq4 + i][k0]);
            #pragma unroll
            for (int kk = 0; kk < 4; ++kk)
                ev[kk] = *reinterpret_cast<const float4*>(&Et[k0 + kk][4 * tq4]);
            #pragma unroll
            for (int kk = 0; kk < 4; ++kk) {
                const float e0 = ((const float*)&ev[kk])[0];
                const float e1 = ((const float*)&ev[kk])[1];
                const float e2 = ((const float*)&ev[kk])[2];
                const float e3 = ((const float*)&ev[kk])[3];
                #pragma unroll
                for (int i = 0; i < 4; ++i) {
                    const float xvk = ((const float*)&xv[i])[kk];
                    acc[i][0] += xvk * e0; acc[i][1] += xvk * e1;
                    acc[i][2] += xvk * e2; acc[i][3] += xvk * e3;
                }
            }
        }
        float* WP = ws + OFF_WPART + (size_t)kc * (64 * 256);
        #pragma unroll
        for (int i = 0; i < 4; ++i)
            *reinterpret_cast<float4*>(
                WP + (size_t)(4 * bq4 + i) * 256 + tqb * 64 + 4 * tq4) =
                make_float4(acc[i][0], acc[i][1], acc[i][2], acc[i][3]);
    } else if (blk < 320) {
        // ---- MT 32x32 tile ----
        const int mb = blk - 256;
        float (*Aq)[33] = (float(*)[33])smem;
        float (*Bk)[33] = (float(*)[33])(smem + 4224);
        const int bi = mb >> 3, bj = mb & 7;
        const int I0 = bi * 32, J0 = bj * 32;
        const int lr = tid >> 5;   // 0..7
        const int lc = tid & 31;   // 0..31
        float acc[4] = {0.f, 0.f, 0.f, 0.f};
        for (int oc = 0; oc < DQK; oc += 32) {
            #pragma unroll
            for (int r = 0; r < 4; ++r) {
                int oo = lr + 8 * r;
                Aq[oo][lc] = Wq[(size_t)(oc + oo) * DE + I0 + lc];
                Bk[oo][lc] = Wk[(size_t)(oc + oo) * DE + J0 + lc];
            }
            __syncthreads();
            #pragma unroll
            for (int oo = 0; oo < 32; ++oo) {
                float bv = Bk[oo][lc];
                #pragma unroll
                for (int r = 0; r < 4; ++r)
                    acc[r] += Aq[oo][lr + 8 * r] * bv;
            }
            __syncthreads();
        }
        float* MT = ws + OFF_MT;
        #pragma unroll
        for (int r = 0; r < 4; ++r)
            MT[(size_t)(I0 + lr + 8 * r) * DE + (J0 + lc)] = acc[r] * SCALE;
    } else {
        // ---- aux ----
        float* sb0 = (float*)smem;          // bq
        float* sb1 = sb0 + 256;             // bk
        float* rp  = sb1 + 256;
        float* aux = ws + OFF_AUX;
        sb0[tid] = bq[tid];
        sb1[tid] = bk[tid];
        __syncthreads();
        float a0 = 0.f, a1 = 0.f;
        #pragma unroll 8
        for (int o = 0; o < DQK; ++o) {
            a0 += Wk[(size_t)o * DE + tid] * sb0[o];
            a1 += Wq[(size_t)o * DE + tid] * sb1[o];
        }
        aux[tid]       = a0 * SCALE;   // m0
        aux[256 + tid] = a1 * SCALE;   // g1
        rp[tid] = sb0[tid] * sb1[tid];
        __syncthreads();
        if (tid < 128) rp[tid] += rp[tid + 128];
        __syncthreads();
        if (tid < 64) {
            float v = rp[tid] + rp[tid + 64];
            for (int off = 32; off; off >>= 1) v += __shfl_xor(v, off);
            if (tid == 0) aux[512] = v * SCALE;   // g0
        }
    }
}

// ---------------------------------------------------------------------------
// KB: 256 blocks = (b, t-quarter tq) x 256 threads:
//   w[t] = sum_kc WPART[kc][b][t]   (full 256-dim, redundant per tq — cheap)
//   s    = sum_d x[b][d]
//   z[tq*64+tl] = sum_d2 w[d2]*MT[d2][t] + s*m0[t]   (d2 split 4-way + LDS tree)
//   c[b] = g1.w + s*g0                               (tq==0 blocks only)
// ---------------------------------------------------------------------------
__global__ __launch_bounds__(256) void kB(
    const float* __restrict__ x, float* __restrict__ ws)
{
    const int blk = blockIdx.x;
    const int b = blk >> 2, tq = blk & 3;
    const int tid = threadIdx.x;
    __shared__ float wl[256];
    __shared__ float red[256];
    __shared__ float s_s;

    // w[t]: reduce partials (coalesced 256B/wave per kc, 64 independent loads)
    float w = 0.f;
    #pragma unroll 8
    for (int kc = 0; kc < NKC; ++kc)
        w += ws[OFF_WPART + (size_t)kc * (64 * 256) + (size_t)b * 256 + tid];
    wl[tid] = w;

    // s[b]: tree reduce of x row
    float ps = 0.f;
    const float4* xr = reinterpret_cast<const float4*>(x + (size_t)b * D);
    #pragma unroll 8
    for (int i = tid; i < D / 4; i += 256) {
        float4 v = xr[i];
        ps += (v.x + v.y) + (v.z + v.w);
    }
    red[tid] = ps;
    __syncthreads();
    if (tid < 128) red[tid] += red[tid + 128];
    __syncthreads();
    if (tid < 64) {
        float v = red[tid] + red[tid + 64];
        for (int off = 32; off; off >>= 1) v += __shfl_xor(v, off);
        if (tid == 0) s_s = v;
    }
    __syncthreads();
    const float sv = s_s;

    // z: thread (tl = tid&63, dq = tid>>6); partial over 64 d2's
    const int tl = tid & 63, dq = tid >> 6;
    const int t = tq * 64 + tl;
    float zp = 0.f;
    #pragma unroll 8
    for (int i = 0; i < 64; ++i) {
        const int d2 = dq * 64 + i;
        zp += wl[d2] * ws[OFF_MT + (size_t)d2 * 256 + t];
    }
    __syncthreads();                 // red free for reuse
    red[tid] = zp;
    __syncthreads();
    if (tid < 64) {
        float z = red[tid] + red[tid + 64] + red[tid + 128] + red[tid + 192]
                + sv * ws[OFF_AUX + tq * 64 + tid];
        ws[OFF_Z + (size_t)(tq * 64 + tid) * B + b] = z;   // [t][b]
    }

    // c[b] (block-uniform branch; barriers safe)
    if (tq == 0) {
        __syncthreads();
        red[tid] = ws[OFF_AUX + 256 + tid] * wl[tid];
        __syncthreads();
        if (tid < 128) red[tid] += red[tid + 128];
        __syncthreads();
        if (tid < 64) {
            float v = red[tid] + red[tid + 64];
            for (int off = 32; off; off >>= 1) v += __shfl_xor(v, off);
            if (tid == 0) ws[OFF_C + b] = v + sv * ws[OFF_AUX + 512];
        }
    }
}

// ---------------------------------------------------------------------------
// KC: 256 blocks x (32 d-rows x 64 b).  F[d][b] = sum_t E[d+1][t]*Z[t][b];
//     y = x*(1 + F + c).  Thread tile 2d x 4b, tt chunked by 4 (all-float4 LDS).
// ---------------------------------------------------------------------------
__global__ __launch_bounds__(256, 2) void kC(
    const float* __restrict__ x, const float* __restrict__ E,
    const float* __restrict__ ws, float* __restrict__ y)
{
    const int d0  = blockIdx.x * 32;
    const int tid = threadIdx.x;

    __shared__ float Zl[256][64];     // 64 KB, [t][b]
    __shared__ float Et[32][68];      // E tile; reused as F after compute

    // stage Z: all 16384 floats via float4 (16 coalesced iters)
    #pragma unroll
    for (int i = 0; i < 16; ++i) {
        int f4 = i * 256 + tid;
        float4 v = *reinterpret_cast<const float4*>(ws + OFF_Z + 4 * (size_t)f4);
        *reinterpret_cast<float4*>(&Zl[0][0] + 4 * f4) = v;
    }
    __syncthreads();

    const int dq  = tid >> 4;   // 0..15 -> d = 2*dq
    const int bq4 = tid & 15;   // 0..15 -> b = 4*bq4
    float acc[2][4] = {};

    for (int ks = 0; ks < 4; ++ks) {
        // stage E tile [32 d][64 t]
        #pragma unroll
        for (int i = 0; i < 2; ++i) {
            int f4 = i * 256 + tid;        // [32 rows][16 f4]
            int r = f4 >> 4, c4 = f4 & 15;
            float4 v = *reinterpret_cast<const float4*>(
                E + (size_t)(d0 + r + 1) * DE + ks * 64 + 4 * c4);
            *reinterpret_cast<float4*>(&Et[r][4 * c4]) = v;
        }
        __syncthreads();
        #pragma unroll 2
        for (int t0 = 0; t0 < 64; t0 += 4) {
            float4 zv[4];
            #pragma unroll
            for (int kk = 0; kk < 4; ++kk)
                zv[kk] = *reinterpret_cast<const float4*>(
                    &Zl[ks * 64 + t0 + kk][4 * bq4]);
            const float4 e0v = *reinterpret_cast<const float4*>(&Et[2 * dq + 0][t0]);
            const float4 e1v = *reinterpret_cast<const float4*>(&Et[2 * dq + 1][t0]);
            #pragma unroll
            for (int kk = 0; kk < 4; ++kk) {
                const float e0 = ((const float*)&e0v)[kk];
                const float e1 = ((const float*)&e1v)[kk];
                acc[0][0] += e0 * zv[kk].x; acc[0][1] += e0 * zv[kk].y;
                acc[0][2] += e0 * zv[kk].z; acc[0][3] += e0 * zv[kk].w;
                acc[1][0] += e1 * zv[kk].x; acc[1][1] += e1 * zv[kk].y;
                acc[1][2] += e1 * zv[kk].z; acc[1][3] += e1 * zv[kk].w;
            }
        }
        __syncthreads();
    }

    // stash F into Et storage: F[d_local][b]
    #pragma unroll
    for (int i = 0; i < 2; ++i)
        *reinterpret_cast<float4*>(&Et[2 * dq + i][4 * bq4]) =
            make_float4(acc[i][0], acc[i][1], acc[i][2], acc[i][3]);
    __syncthreads();

    // y = x * (1 + F + c): thread -> b = tid>>2, 8 d's
    {
        const int b  = tid >> 2;
        const int ds = (tid & 3) * 8;
        const float cc = ws[OFF_C + b];
        const float* xr = x + (size_t)b * D + d0 + ds;
        float*       yr = y + (size_t)b * D + d0 + ds;
        #pragma unroll
        for (int k4 = 0; k4 < 2; ++k4) {
            float4 xv = *reinterpret_cast<const float4*>(xr + 4 * k4);
            float4 yv;
            yv.x = xv.x * (1.f + Et[ds + 4 * k4 + 0][b] + cc);
            yv.y = xv.y * (1.f + Et[ds + 4 * k4 + 1][b] + cc);
            yv.z = xv.z * (1.f + Et[ds + 4 * k4 + 2][b] + cc);
            yv.w = xv.w * (1.f + Et[ds + 4 * k4 + 3][b] + cc);
            *reinterpret_cast<float4*>(yr + 4 * k4) = yv;
        }
    }
}

extern "C" void kernel_launch(void* const* d_in, const int* in_sizes, int n_in,
                              void* d_out, int out_size, void* d_ws, size_t ws_size,
                              hipStream_t stream) {
    // inputs: t, x[B*D], E[(D+1)*DE], Wq[DQK*DE], bq[DQK], Wk[DQK*DE], bk[DQK]
    const float* x  = (const float*)d_in[1];
    const float* E  = (const float*)d_in[2];
    const float* Wq = (const float*)d_in[3];
    const float* bq = (const float*)d_in[4];
    const float* Wk = (const float*)d_in[5];
    const float* bk = (const float*)d_in[6];
    float* y  = (float*)d_out;
    float* ws = (float*)d_ws;

    hipLaunchKernelGGL(kA, dim3(321), dim3(256), 0, stream, x, E, Wq, bq, Wk, bk, ws);
    hipLaunchKernelGGL(kB, dim3(256), dim3(256), 0, stream, x, ws);
    hipLaunchKernelGGL(kC, dim3(256), dim3(256), 0, stream, x, E, ws, y);
}